// Round 1
// baseline (360.767 us; speedup 1.0000x reference)
//
#include <hip/hip_runtime.h>
#include <cstdint>
#include <cstddef>

#define Ndim 8
#define Odim 32
#define Cdim 16
#define Hdim 512
#define Rdim 8

typedef _Float16 half2_t __attribute__((ext_vector_type(2)));

#if defined(__has_builtin)
#if __has_builtin(__builtin_amdgcn_fdot2)
#define HAVE_FDOT2 1
#endif
#endif

__device__ __forceinline__ float fdot2f(half2_t a, half2_t b, float acc) {
#ifdef HAVE_FDOT2
    return __builtin_amdgcn_fdot2(a, b, acc, false);
#else
    return acc + (float)a[0] * (float)b[0] + (float)a[1] * (float)b[1];
#endif
}

union U16 { uint4 u; half2_t h[4]; };

// PASS 0: compute P tile, reduce to row/col partial sums (no atomics when ATOMIC=0).
// PASS 1: recompute P tile, combine with finalized RS/CS + bias, write out (diag zeroed).
template<int PASS, int ATOMIC>
__global__ __launch_bounds__(256)
void sylo_main(const float* __restrict__ Xg, const float* __restrict__ Lg,
               const float* __restrict__ biasg, const float* __restrict__ coupg,
               float* __restrict__ outg, float* __restrict__ rsp, float* __restrict__ csp)
{
    const int tid = threadIdx.x;
    const int bw = blockIdx.x, bh = blockIdx.y;
    const int h0 = bh * 16, w0 = bw * 16;
    const int i = tid >> 4, j = tid & 15;       // pixel (i,j); wave = 4 rows x 16 cols
    const int hh = h0 + i, ww = w0 + j;

    __shared__ __align__(16) _Float16 lh[Cdim][16][Rdim];  // signed (x coupling) h-side
    __shared__ __align__(16) _Float16 lw[Cdim][16][Rdim];  // w-side
    __shared__ float cs_l[4][Ndim][16];                    // per-wave col partials (PASS 0)

    // ---- X prologue: this thread's pixel, all (c,n), packed f16 c-pairs in regs ----
    half2_t x2[64];   // [cpair(8)][n(8)]
    {
        const size_t pix = (size_t)hh * Hdim + ww;
        #pragma unroll
        for (int c = 0; c < Cdim; c += 2) {
            #pragma unroll
            for (int n = 0; n < Ndim; ++n) {
                float a = Xg[(size_t)(n * Cdim + c    ) * (Hdim * Hdim) + pix];
                float b = Xg[(size_t)(n * Cdim + c + 1) * (Hdim * Hdim) + pix];
                half2_t h; h[0] = (_Float16)a; h[1] = (_Float16)b;
                x2[(c >> 1) * 8 + n] = h;
            }
        }
    }

    const int sc = tid >> 4, sk = tid & 15;     // staging: thread -> (channel, row)

    for (int o = 0; o < Odim; ++o) {
        // ---- stage L[o] into LDS as f16 (sign folded into h-side) ----
        {
            const float* lhp = &Lg[((size_t)(o * Cdim + sc) * Hdim + (h0 + sk)) * Rdim];
            const float* lwp = &Lg[((size_t)(o * Cdim + sc) * Hdim + (w0 + sk)) * Rdim];
            const float* cpp = &coupg[(size_t)(o * Cdim + sc) * Rdim];
            float4 l0 = ((const float4*)lhp)[0], l1 = ((const float4*)lhp)[1];
            float4 m0 = ((const float4*)lwp)[0], m1 = ((const float4*)lwp)[1];
            float4 c0 = ((const float4*)cpp)[0], c1 = ((const float4*)cpp)[1];
            U16 hu, wu;
            hu.h[0][0] = (_Float16)(l0.x * c0.x); hu.h[0][1] = (_Float16)(l0.y * c0.y);
            hu.h[1][0] = (_Float16)(l0.z * c0.z); hu.h[1][1] = (_Float16)(l0.w * c0.w);
            hu.h[2][0] = (_Float16)(l1.x * c1.x); hu.h[2][1] = (_Float16)(l1.y * c1.y);
            hu.h[3][0] = (_Float16)(l1.z * c1.z); hu.h[3][1] = (_Float16)(l1.w * c1.w);
            wu.h[0][0] = (_Float16)m0.x; wu.h[0][1] = (_Float16)m0.y;
            wu.h[1][0] = (_Float16)m0.z; wu.h[1][1] = (_Float16)m0.w;
            wu.h[2][0] = (_Float16)m1.x; wu.h[2][1] = (_Float16)m1.y;
            wu.h[3][0] = (_Float16)m1.z; wu.h[3][1] = (_Float16)m1.w;
            *(uint4*)&lh[sc][sk][0] = hu.u;
            *(uint4*)&lw[sc][sk][0] = wu.u;
        }
        __syncthreads();

        // ---- T per (c) for this pixel, packed to f16 c-pairs; then P over (c,n) ----
        float p[Ndim];
        #pragma unroll
        for (int n = 0; n < Ndim; ++n) p[n] = 0.f;

        half2_t t2[8];
        float tprev = 0.f;
        #pragma unroll
        for (int c = 0; c < Cdim; ++c) {
            U16 A, B;
            A.u = *(const uint4*)&lh[c][i][0];   // broadcast across j-lanes
            B.u = *(const uint4*)&lw[c][j][0];   // 2-way bank alias (free)
            float t = 0.f;
            #pragma unroll
            for (int r = 0; r < 4; ++r) t = fdot2f(A.h[r], B.h[r], t);
            if (c & 1) { half2_t hp; hp[0] = (_Float16)tprev; hp[1] = (_Float16)t; t2[c >> 1] = hp; }
            else tprev = t;
        }

        #pragma unroll
        for (int cp = 0; cp < 8; ++cp) {
            #pragma unroll
            for (int n = 0; n < Ndim; ++n)
                p[n] = fdot2f(t2[cp], x2[cp * 8 + n], p[n]);
        }

        if (PASS == 0) {
            #pragma unroll
            for (int n = 0; n < Ndim; ++n) {
                // row sum over j (16 lanes)
                float r = p[n];
                r += __shfl_xor(r, 1);
                r += __shfl_xor(r, 2);
                r += __shfl_xor(r, 4);
                r += __shfl_xor(r, 8);
                if (j == n) {
                    if (ATOMIC) atomicAdd(&rsp[((size_t)n * Odim + o) * Hdim + hh], r);
                    else rsp[(((size_t)bw * Ndim + n) * Odim + o) * Hdim + hh] = r;
                }
                // col partial over the wave's 4 rows
                float cc = p[n];
                cc += __shfl_xor(cc, 16);
                cc += __shfl_xor(cc, 32);
                if ((i & 3) == (n & 3)) cs_l[i >> 2][n][j] = cc;
            }
            __syncthreads();
            if (tid < 128) {
                int nn = tid >> 4, jj = tid & 15;
                float v = cs_l[0][nn][jj] + cs_l[1][nn][jj] + cs_l[2][nn][jj] + cs_l[3][nn][jj];
                if (ATOMIC) atomicAdd(&csp[((size_t)nn * Odim + o) * Hdim + (w0 + jj)], v);
                else csp[(((size_t)bh * Ndim + nn) * Odim + o) * Hdim + (w0 + jj)] = v;
            }
            __syncthreads();
        } else {
            float bb = biasg[o];
            #pragma unroll
            for (int n = 0; n < Ndim; ++n) {
                float v = rsp[((size_t)n * Odim + o) * Hdim + hh]
                        + csp[((size_t)n * Odim + o) * Hdim + ww]
                        - p[n] + bb;
                if (hh == ww) v = 0.f;
                outg[(((size_t)n * Odim + o) * Hdim + hh) * Hdim + ww] = v;
            }
            __syncthreads();   // lh/lw reused next o
        }
    }
}

// Sum the 32 per-block-column partials into final RS / CS.
__global__ __launch_bounds__(256)
void sylo_reduce(const float* __restrict__ rspart, const float* __restrict__ cspart,
                 float* __restrict__ rs, float* __restrict__ cs)
{
    int t = blockIdx.x * 256 + threadIdx.x;   // 0 .. 131071
    float a = 0.f, b = 0.f;
    #pragma unroll
    for (int k = 0; k < 32; ++k) {
        a += rspart[(size_t)k * 131072 + t];
        b += cspart[(size_t)k * 131072 + t];
    }
    rs[t] = a;
    cs[t] = b;
}

extern "C" void kernel_launch(void* const* d_in, const int* in_sizes, int n_in,
                              void* d_out, int out_size, void* d_ws, size_t ws_size,
                              hipStream_t stream)
{
    const float* X    = (const float*)d_in[0];
    const float* L    = (const float*)d_in[1];
    const float* bias = (const float*)d_in[2];
    const float* coup = (const float*)d_in[3];
    float* out = (float*)d_out;

    const size_t FIN  = (size_t)Ndim * Odim * Hdim;   // 131072
    const size_t PART = FIN * 32;                     // 4194304
    const size_t need = (2 * PART + 2 * FIN) * sizeof(float);

    dim3 grid(32, 32), blk(256);
    if (ws_size >= need) {
        float* rspart = (float*)d_ws;
        float* cspart = rspart + PART;
        float* rs = cspart + PART;
        float* cs = rs + FIN;
        sylo_main<0, 0><<<grid, blk, 0, stream>>>(X, L, bias, coup, out, rspart, cspart);
        sylo_reduce<<<dim3(512), blk, 0, stream>>>(rspart, cspart, rs, cs);
        sylo_main<1, 0><<<grid, blk, 0, stream>>>(X, L, bias, coup, out, rs, cs);
    } else {
        float* rs = (float*)d_ws;
        float* cs = rs + FIN;
        hipMemsetAsync(d_ws, 0, 2 * FIN * sizeof(float), stream);
        sylo_main<0, 1><<<grid, blk, 0, stream>>>(X, L, bias, coup, out, rs, cs);
        sylo_main<1, 0><<<grid, blk, 0, stream>>>(X, L, bias, coup, out, rs, cs);
    }
}

// Round 2
// 357.110 us; speedup vs baseline: 1.0102x; 1.0102x over previous
//
#include <hip/hip_runtime.h>
#include <cstdint>
#include <cstddef>

#define Ndim 8
#define Odim 32
#define Cdim 16
#define Hdim 512
#define Rdim 8
#define TW 64
#define TH 8
#define NBW (Hdim/TW)   // 8 w-blocks
#define NBH (Hdim/TH)   // 64 h-blocks

typedef _Float16 half2_t __attribute__((ext_vector_type(2)));

union U16 { uint4 u; half2_t h[4]; _Float16 f[8]; };

__device__ __forceinline__ half2_t pk(float a, float b) {
    half2_t h; h[0] = (_Float16)a; h[1] = (_Float16)b; return h;
}

#if defined(__has_builtin)
#if __has_builtin(__builtin_amdgcn_fdot2)
#define HAVE_FDOT2 1
#endif
#endif

__device__ __forceinline__ float fdot2f(half2_t a, half2_t b, float acc) {
#ifdef HAVE_FDOT2
    return __builtin_amdgcn_fdot2(a, b, acc, false);
#else
    return acc + (float)a[0] * (float)b[0] + (float)a[1] * (float)b[1];
#endif
}

// v_add with DPP ladder: full-wave64 sum, result valid in lanes 48..63.
template<int CTRL>
__device__ __forceinline__ float dppadd(float v) {
    return v + __int_as_float(__builtin_amdgcn_update_dpp(
        0, __float_as_int(v), CTRL, 0xf, 0xf, true));
}
__device__ __forceinline__ float wave_sum63(float v) {
    v = dppadd<0xB1>(v);    // xor1  (quad_perm [1,0,3,2])
    v = dppadd<0x4E>(v);    // xor2  (quad_perm [2,3,0,1])
    v = dppadd<0x141>(v);   // row_half_mirror
    v = dppadd<0x140>(v);   // row_mirror
    v = dppadd<0x142>(v);   // row_bcast15
    v = dppadd<0x143>(v);   // row_bcast31
    return v;
}

// Pre-pack L into f16: lsig = L*coupling (h-side), lraw = L (w-side).
__global__ __launch_bounds__(256)
void sylo_prep(const float* __restrict__ L, const float* __restrict__ coup,
               uint4* __restrict__ lsig, uint4* __restrict__ lraw)
{
    int row = blockIdx.x * 256 + threadIdx.x;      // (o*C + c)*H + h, < 262144
    int oc = row >> 9;
    const float4* lp = (const float4*)(L + (size_t)row * Rdim);
    const float4* cp = (const float4*)(coup + (size_t)oc * Rdim);
    float4 l0 = lp[0], l1 = lp[1];
    float4 c0 = cp[0], c1 = cp[1];
    U16 s, r;
    s.h[0] = pk(l0.x * c0.x, l0.y * c0.y); s.h[1] = pk(l0.z * c0.z, l0.w * c0.w);
    s.h[2] = pk(l1.x * c1.x, l1.y * c1.y); s.h[3] = pk(l1.z * c1.z, l1.w * c1.w);
    r.h[0] = pk(l0.x, l0.y); r.h[1] = pk(l0.z, l0.w);
    r.h[2] = pk(l1.x, l1.y); r.h[3] = pk(l1.z, l1.w);
    lsig[row] = s.u;
    lraw[row] = r.u;
}

// MODE 0: partial-sum buffers (rsp/csp) + reduce kernel.
// MODE 1: atomicAdd into rs/cs, L16 from prep.
// MODE 2: atomicAdd, stage/convert L from fp32 inline (minimal ws).
template<int PASS, int MODE>
__global__ __launch_bounds__(256, 2)
void sylo_main(const float* __restrict__ Xg, const float* __restrict__ Lg,
               const float* __restrict__ coupg, const float* __restrict__ biasg,
               const uint4* __restrict__ lsig, const uint4* __restrict__ lraw,
               float* __restrict__ outg,
               float* __restrict__ rsp, float* __restrict__ csp,
               float* __restrict__ rs, float* __restrict__ cs)
{
    const int tid = threadIdx.x;
    const int j = tid & 63, iw = tid >> 6;         // wave = one 64-wide row pair owner
    const int bw = blockIdx.x, bh = blockIdx.y;
    const int w0 = bw * TW, h0 = bh * TH;
    const int hh0 = h0 + iw, hh1 = h0 + iw + 4;    // this thread's two rows
    const int ww = w0 + j;

    __shared__ __align__(16) _Float16 lw[Cdim][TW][Rdim];  // 16 KB, w-side f16
    __shared__ float csl[4][Ndim][TW];                     // 8 KB, col partials

    // ---- X prologue: both pixels, all (c,n), f16 c-pairs in registers ----
    half2_t xa[64], xb[64];
    {
        const size_t HH = (size_t)Hdim * Hdim;
        const size_t qa = (size_t)hh0 * Hdim + ww;
        const size_t qb = (size_t)hh1 * Hdim + ww;
        #pragma unroll
        for (int c = 0; c < Cdim; c += 2) {
            #pragma unroll
            for (int n = 0; n < Ndim; ++n) {
                const float* p0 = Xg + (size_t)(n * Cdim + c) * HH;
                const float* p1 = Xg + (size_t)(n * Cdim + c + 1) * HH;
                xa[(c >> 1) * 8 + n] = pk(p0[qa], p1[qa]);
                xb[(c >> 1) * 8 + n] = pk(p0[qb], p1[qb]);
            }
        }
    }

    const int ru0 = __builtin_amdgcn_readfirstlane(hh0);  // wave-uniform rows -> s_load
    const int ru1 = __builtin_amdgcn_readfirstlane(hh1);

    for (int o = 0; o < Odim; ++o) {
        // ---- stage w-side L tile into LDS ----
        #pragma unroll
        for (int k = 0; k < 4; ++k) {
            int e = tid + k * 256;
            int c = e >> 6, w = e & 63;
            uint4 v;
            if (MODE < 2) {
                v = lraw[(size_t)(o * Cdim + c) * Hdim + w0 + w];
            } else {
                const float4* gp = (const float4*)(Lg + ((size_t)(o * Cdim + c) * Hdim + w0 + w) * Rdim);
                float4 l0 = gp[0], l1 = gp[1];
                U16 t;
                t.h[0] = pk(l0.x, l0.y); t.h[1] = pk(l0.z, l0.w);
                t.h[2] = pk(l1.x, l1.y); t.h[3] = pk(l1.z, l1.w);
                v = t.u;
            }
            *(uint4*)&lw[c][w][0] = v;
        }
        __syncthreads();

        // ---- T per (c, both rows): A from scalar loads, B from LDS ----
        float pa[Ndim], pb[Ndim];
        #pragma unroll
        for (int n = 0; n < Ndim; ++n) { pa[n] = 0.f; pb[n] = 0.f; }

        half2_t t2a[8], t2b[8];
        float tpa = 0.f, tpb = 0.f;
        #pragma unroll
        for (int c = 0; c < Cdim; ++c) {
            U16 A0, A1, B;
            if (MODE < 2) {
                A0.u = lsig[(size_t)(o * Cdim + c) * Hdim + ru0];
                A1.u = lsig[(size_t)(o * Cdim + c) * Hdim + ru1];
            } else {
                const float4* a0 = (const float4*)(Lg + ((size_t)(o * Cdim + c) * Hdim + ru0) * Rdim);
                const float4* a1 = (const float4*)(Lg + ((size_t)(o * Cdim + c) * Hdim + ru1) * Rdim);
                const float4* cpp = (const float4*)(coupg + (size_t)(o * Cdim + c) * Rdim);
                float4 l0 = a0[0], l1 = a0[1], m0 = a1[0], m1 = a1[1];
                float4 c0 = cpp[0], c1 = cpp[1];
                A0.h[0] = pk(l0.x * c0.x, l0.y * c0.y); A0.h[1] = pk(l0.z * c0.z, l0.w * c0.w);
                A0.h[2] = pk(l1.x * c1.x, l1.y * c1.y); A0.h[3] = pk(l1.z * c1.z, l1.w * c1.w);
                A1.h[0] = pk(m0.x * c0.x, m0.y * c0.y); A1.h[1] = pk(m0.z * c0.z, m0.w * c0.w);
                A1.h[2] = pk(m1.x * c1.x, m1.y * c1.y); A1.h[3] = pk(m1.z * c1.z, m1.w * c1.w);
            }
            B.u = *(const uint4*)&lw[c][j][0];
            float ta = 0.f, tb = 0.f;
            #pragma unroll
            for (int r = 0; r < 4; ++r) {
                ta = fdot2f(A0.h[r], B.h[r], ta);
                tb = fdot2f(A1.h[r], B.h[r], tb);
            }
            if (c & 1) { t2a[c >> 1] = pk(tpa, ta); t2b[c >> 1] = pk(tpb, tb); }
            else       { tpa = ta; tpb = tb; }
        }

        // ---- P over (c,n), both pixels ----
        #pragma unroll
        for (int cp8 = 0; cp8 < 8; ++cp8) {
            #pragma unroll
            for (int n = 0; n < Ndim; ++n) {
                pa[n] = fdot2f(t2a[cp8], xa[cp8 * 8 + n], pa[n]);
                pb[n] = fdot2f(t2b[cp8], xb[cp8 * 8 + n], pb[n]);
            }
        }

        if (PASS == 0) {
            #pragma unroll
            for (int n = 0; n < Ndim; ++n) {
                float ra = wave_sum63(pa[n]);   // row sums on VALU (DPP), not DS pipe
                float rb = wave_sum63(pb[n]);
                if (j == 63) {
                    size_t i0 = (size_t)(n * Odim + o) * Hdim;
                    if (MODE == 0) {
                        rsp[(size_t)bw * ((size_t)Ndim * Odim * Hdim) + i0 + hh0] = ra;
                        rsp[(size_t)bw * ((size_t)Ndim * Odim * Hdim) + i0 + hh1] = rb;
                    } else {
                        atomicAdd(&rs[i0 + hh0], ra);
                        atomicAdd(&rs[i0 + hh1], rb);
                    }
                }
                csl[iw][n][j] = pa[n] + pb[n];
            }
            __syncthreads();
            #pragma unroll
            for (int k = 0; k < 2; ++k) {
                int e = tid + k * 256;
                int n = e >> 6, jj = e & 63;
                float v = csl[0][n][jj] + csl[1][n][jj] + csl[2][n][jj] + csl[3][n][jj];
                size_t idx = (size_t)(n * Odim + o) * Hdim + w0 + jj;
                if (MODE == 0) csp[(size_t)bh * ((size_t)Ndim * Odim * Hdim) + idx] = v;
                else atomicAdd(&cs[idx], v);
            }
            __syncthreads();
        } else {
            float bb = biasg[o];
            #pragma unroll
            for (int n = 0; n < Ndim; ++n) {
                size_t i0 = (size_t)(n * Odim + o) * Hdim;
                float rsa = rs[i0 + hh0];
                float rsb = rs[i0 + hh1];
                float cv  = cs[i0 + ww];
                float va = rsa + cv - pa[n] + bb;
                float vb = rsb + cv - pb[n] + bb;
                if (hh0 == ww) va = 0.f;
                if (hh1 == ww) vb = 0.f;
                outg[(i0 + hh0) * Hdim + ww] = va;
                outg[(i0 + hh1) * Hdim + ww] = vb;
            }
            __syncthreads();   // lw reused next o
        }
    }
}

__global__ __launch_bounds__(256)
void sylo_reduce(const float* __restrict__ rsp, const float* __restrict__ csp,
                 float* __restrict__ rs, float* __restrict__ cs)
{
    int t = blockIdx.x * 256 + threadIdx.x;   // < 131072
    const size_t S = (size_t)Ndim * Odim * Hdim;
    float a = 0.f;
    #pragma unroll
    for (int k = 0; k < NBW; ++k) a += rsp[(size_t)k * S + t];
    rs[t] = a;
    float b = 0.f;
    #pragma unroll
    for (int k = 0; k < NBH; ++k) b += csp[(size_t)k * S + t];
    cs[t] = b;
}

extern "C" void kernel_launch(void* const* d_in, const int* in_sizes, int n_in,
                              void* d_out, int out_size, void* d_ws, size_t ws_size,
                              hipStream_t stream)
{
    const float* X    = (const float*)d_in[0];
    const float* L    = (const float*)d_in[1];
    const float* bias = (const float*)d_in[2];
    const float* coup = (const float*)d_in[3];
    float* out = (float*)d_out;

    const size_t S    = (size_t)Ndim * Odim * Hdim;    // 131072
    const size_t NL16 = (size_t)Odim * Cdim * Hdim;    // 262144 rows of 16B
    const size_t need0 = NL16 * 16 * 2 + (NBW + NBH + 2) * S * 4;  // ~47 MB
    const size_t need1 = NL16 * 16 * 2 + 2 * S * 4;                // ~9.4 MB
    dim3 grid(NBW, NBH), blk(256);

    if (ws_size >= need0) {
        uint4* lsig = (uint4*)d_ws;
        uint4* lraw = lsig + NL16;
        float* rsp = (float*)(lraw + NL16);
        float* csp = rsp + (size_t)NBW * S;
        float* rs  = csp + (size_t)NBH * S;
        float* cs  = rs + S;
        sylo_prep<<<dim3(1024), blk, 0, stream>>>(L, coup, lsig, lraw);
        sylo_main<0,0><<<grid, blk, 0, stream>>>(X, L, coup, bias, lsig, lraw, out, rsp, csp, rs, cs);
        sylo_reduce<<<dim3(512), blk, 0, stream>>>(rsp, csp, rs, cs);
        sylo_main<1,0><<<grid, blk, 0, stream>>>(X, L, coup, bias, lsig, lraw, out, rsp, csp, rs, cs);
    } else if (ws_size >= need1) {
        uint4* lsig = (uint4*)d_ws;
        uint4* lraw = lsig + NL16;
        float* rs = (float*)(lraw + NL16);
        float* cs = rs + S;
        hipMemsetAsync(rs, 0, 2 * S * sizeof(float), stream);
        sylo_prep<<<dim3(1024), blk, 0, stream>>>(L, coup, lsig, lraw);
        sylo_main<0,1><<<grid, blk, 0, stream>>>(X, L, coup, bias, lsig, lraw, out, nullptr, nullptr, rs, cs);
        sylo_main<1,1><<<grid, blk, 0, stream>>>(X, L, coup, bias, lsig, lraw, out, nullptr, nullptr, rs, cs);
    } else {
        float* rs = (float*)d_ws;
        float* cs = rs + S;
        hipMemsetAsync(rs, 0, 2 * S * sizeof(float), stream);
        sylo_main<0,2><<<grid, blk, 0, stream>>>(X, L, coup, bias, nullptr, nullptr, out, nullptr, nullptr, rs, cs);
        sylo_main<1,2><<<grid, blk, 0, stream>>>(X, L, coup, bias, nullptr, nullptr, out, nullptr, nullptr, rs, cs);
    }
}